// Round 1
// 16455.110 us; speedup vs baseline: 1.1028x; 1.1028x over previous
//
#include <hip/hip_runtime.h>
#include <stdint.h>

#define T_STEPS 8192
#define IN_DIM  512
#define HID     1024
#define G4      4096
#define NBLK    64          // recurrent blocks (1 per CU, all co-resident)
#define NW      16          // waves per block

typedef unsigned long long u64;

// ---------------------------------------------------------------------------
// Kernel 1: x_gates[t][r] = sum_k input[t][k] * W_ih[r][k] + b_ih[r] + b_hh[r]
// fp32 tiled GEMM (NT), 128x128 tile, K-tile 8, 256 threads, 8x8 per thread.
// (unchanged from R9 — ~250us, not the bottleneck)
// ---------------------------------------------------------------------------
__global__ __launch_bounds__(256) void gemm_xgates(
    const float* __restrict__ A,    // [8192][512]
    const float* __restrict__ W,    // [4096][512]
    const float* __restrict__ bih,  // [4096]
    const float* __restrict__ bhh,  // [4096]
    float* __restrict__ xg)         // [8192][4096]
{
    __shared__ float At[8][128];   // k-major A tile
    __shared__ float Bt[8][128];   // k-major W tile
    const int tid = threadIdx.x;
    const int r0 = blockIdx.x * 128;   // gate-row dim (4096)
    const int t0 = blockIdx.y * 128;   // time dim (8192)
    const int tx = tid & 15, ty = tid >> 4;
    const int lrow = tid >> 1;         // 0..127
    const int kq   = (tid & 1) * 4;    // 0 or 4

    float acc[8][8];
#pragma unroll
    for (int i = 0; i < 8; ++i)
#pragma unroll
        for (int j = 0; j < 8; ++j) acc[i][j] = 0.f;

    for (int k0 = 0; k0 < IN_DIM; k0 += 8) {
        float4 av = *(const float4*)&A[(size_t)(t0 + lrow) * IN_DIM + k0 + kq];
        float4 bv = *(const float4*)&W[(size_t)(r0 + lrow) * IN_DIM + k0 + kq];
        __syncthreads();
        At[kq + 0][lrow] = av.x; At[kq + 1][lrow] = av.y;
        At[kq + 2][lrow] = av.z; At[kq + 3][lrow] = av.w;
        Bt[kq + 0][lrow] = bv.x; Bt[kq + 1][lrow] = bv.y;
        Bt[kq + 2][lrow] = bv.z; Bt[kq + 3][lrow] = bv.w;
        __syncthreads();
#pragma unroll
        for (int k = 0; k < 8; ++k) {
            float4 a0 = *(const float4*)&At[k][ty * 8];
            float4 a1 = *(const float4*)&At[k][ty * 8 + 4];
            float4 b0 = *(const float4*)&Bt[k][tx * 8];
            float4 b1 = *(const float4*)&Bt[k][tx * 8 + 4];
            float aa[8] = {a0.x, a0.y, a0.z, a0.w, a1.x, a1.y, a1.z, a1.w};
            float bb[8] = {b0.x, b0.y, b0.z, b0.w, b1.x, b1.y, b1.z, b1.w};
#pragma unroll
            for (int i = 0; i < 8; ++i)
#pragma unroll
                for (int j = 0; j < 8; ++j) acc[i][j] += aa[i] * bb[j];
        }
    }

    float bias[8];
#pragma unroll
    for (int j = 0; j < 8; ++j) {
        int r = r0 + tx * 8 + j;
        bias[j] = bih[r] + bhh[r];
    }
#pragma unroll
    for (int i = 0; i < 8; ++i) {
        int t = t0 + ty * 8 + i;
        float4 o0 = make_float4(acc[i][0] + bias[0], acc[i][1] + bias[1],
                                acc[i][2] + bias[2], acc[i][3] + bias[3]);
        float4 o1 = make_float4(acc[i][4] + bias[4], acc[i][5] + bias[5],
                                acc[i][6] + bias[6], acc[i][7] + bias[7]);
        *(float4*)&xg[(size_t)t * G4 + r0 + tx * 8]     = o0;
        *(float4*)&xg[(size_t)t * G4 + r0 + tx * 8 + 4] = o1;
    }
}

// ---------------------------------------------------------------------------
// Kernel 2 (R10): persistent recurrent LSTM — COLUMN-SPLIT dot, zero barriers.
//
// 64 blocks x 1024 threads (16 waves, 1 block/CU). New decomposition:
//   * wave w polls ONLY h[64w .. 64w+64) — exactly the column chunk its
//     partial dot needs. 1 tagged u64 load/lane/iter (same 1024-slot global
//     coverage as R6's 4x4 quarter-poll → same LLC pressure), 2-deep
//     pipelined to halve detection dead-time.
//   * lane l owns output (gate = l&3, h16 = l>>2); weights
//     wv[k] = Whh[gate*1024 + 16b + h16][64w + k], 64 f32/lane (same reg
//     budget as R6). Chunk h is bounced through a per-wave-private LDS row
//     and consumed via wave-uniform ds_read_b128 broadcasts: 64 FMAs.
//   * partial sums -> LDS + per-wave tag flag (release). Wave 0 (reducer)
//     spin-acquires the 16 flags, tree-sums, quad_perm-exchanges i/f/g/o
//     within lane quads (DPP, no LDS, no divergence), updates c/h, and
//     publishes the block's 16-slot line DIRECTLY (gate==0 lanes, one
//     exec-masked dwordx2 store — single-line publish preserved per R7).
//
// What this deletes from R6's per-step critical path: barrier A (+convoy),
// the poller->LDS->all-waves h redistribution, the lane63->LDS->wave4
// gather hop, and the 24 DPP reduce ops/wave. The 15 non-reducer waves
// fall straight into the NEXT step's poll, so their detection overlaps the
// reduce+publish+LLC flight.
//
// Self-timing safety (no barriers in the loop): tags 1..8192 never collide
// with 0xAA poison; 2-parity hdata/part buffers are safe because block B
// overwriting tag t+2 transitively requires every block's wave (B>>2) to
// have already poll-consumed B's tag-t line (publish(t+2) <= all blocks
// published t+1 <= every block's reduce(t) <= all its waves polled t).
// pflag LDS is zero-initialized before the single pre-loop __syncthreads.
// ---------------------------------------------------------------------------
__device__ __forceinline__ float sigm_f(float x) {
    return __builtin_amdgcn_rcpf(1.f + __expf(-x));
}
__device__ __forceinline__ float tanh_f(float x) {
    x = fminf(fmaxf(x, -15.f), 15.f);
    float e = __expf(2.f * x);
    return (e - 1.f) * __builtin_amdgcn_rcpf(e + 1.f);
}

// Broadcast lane q of each 4-lane quad to the whole quad (DPP quad_perm).
// PAT = q | q<<2 | q<<4 | q<<6 : 0x00, 0x55, 0xAA, 0xFF.
template <int PAT>
__device__ __forceinline__ float quad_bcast(float x) {
    int v = __builtin_amdgcn_update_dpp(0, __float_as_int(x), PAT, 0xf, 0xf, true);
    return __int_as_float(v);
}

__global__ __launch_bounds__(1024, 1) void lstm_rec(
    const float* __restrict__ Whh,   // [4096][1024]
    const float* __restrict__ xg,    // [8192][4096]
    float* __restrict__ hs,          // [(T+1)][1024] (rows 1..T used)
    u64* __restrict__ hdata)         // [2][1024] tagged {tag, f32}
{
    __shared__ float    chunk[NW][64];     // per-wave PRIVATE h chunk bounce
    __shared__ float    part[2][NW][64];   // parity-buffered partial sums
    __shared__ uint32_t pflag[2][NW];      // parity-buffered tag flags

    const int tid  = threadIdx.x;
    const int b    = blockIdx.x;           // 0..63
    const int w    = tid >> 6;             // wave 0..15
    const int l    = tid & 63;             // lane
    const int gate = l & 3;                // i,f,g,o
    const int h16  = l >> 2;               // 0..15 — block-local h index
    const int grow = gate * HID + b * NW + h16;   // gate row in [0,4096)

    // Register-resident weight slice: wv[k4] = Whh[grow][64w + 4k4 .. +3].
    float4 wv[16];
    {
        const float* row = &Whh[(size_t)grow * HID + 64 * w];
#pragma unroll
        for (int k4 = 0; k4 < 16; ++k4) wv[k4] = *(const float4*)&row[4 * k4];
    }
#pragma unroll
    for (int k4 = 0; k4 < 16; ++k4)
        asm volatile("" : "+v"(wv[k4].x), "+v"(wv[k4].y),
                         "+v"(wv[k4].z), "+v"(wv[k4].w));

    if (tid < 2 * NW) ((uint32_t*)pflag)[tid] = 0;
    __syncthreads();    // the ONLY barrier (orders pflag init)

    const bool is_red = (w == 0);
    float c  = 0.f;                        // quad-replicated cell state
    float xv = 0.f, xn = 0.f;              // per-lane x-gate (reducer only)
    if (is_red) xv = xg[grow];             // t = 0

    for (int t = 0; t < T_STEPS; ++t) {
        float a0 = 0.f, a1 = 0.f, a2 = 0.f, a3 = 0.f;
        if (t > 0) {
            // ---- acquire own chunk: 1 tagged load/lane, 2-deep pipeline ---
            const u64* ptr = hdata + (((size_t)(t - 1) & 1) << 10) + 64 * w + l;
            const uint32_t want32 = (uint32_t)t;
            u64 va = __hip_atomic_load(ptr, __ATOMIC_RELAXED, __HIP_MEMORY_SCOPE_AGENT);
            u64 vb = __hip_atomic_load(ptr, __ATOMIC_RELAXED, __HIP_MEMORY_SCOPE_AGENT);
            u64 v;
            for (;;) {
                if (__all((uint32_t)(va >> 32) == want32)) { v = va; break; }
                va = __hip_atomic_load(ptr, __ATOMIC_RELAXED, __HIP_MEMORY_SCOPE_AGENT);
                if (__all((uint32_t)(vb >> 32) == want32)) { v = vb; break; }
                vb = __hip_atomic_load(ptr, __ATOMIC_RELAXED, __HIP_MEMORY_SCOPE_AGENT);
            }
            // ---- partial dot over own 64 columns (LDS broadcast reads) ----
            chunk[w][l] = __uint_as_float((uint32_t)v);
#pragma unroll
            for (int k4 = 0; k4 < 16; ++k4) {
                float4 h4 = *(const float4*)&chunk[w][4 * k4];  // wave-uniform
                a0 = fmaf(wv[k4].x, h4.x, a0);
                a1 = fmaf(wv[k4].y, h4.y, a1);
                a2 = fmaf(wv[k4].z, h4.z, a2);
                a3 = fmaf(wv[k4].w, h4.w, a3);
            }
        }
        const int p = t & 1;
        part[p][w][l] = (a0 + a1) + (a2 + a3);
        if (l == 0)
            __hip_atomic_store(&pflag[p][w], (uint32_t)(t + 1),
                               __ATOMIC_RELEASE, __HIP_MEMORY_SCOPE_WORKGROUP);
        // Non-reducer waves: straight to next step's poll — overlaps the
        // reduce + publish + LLC flight below.

        if (is_red) {
            if (t + 1 < T_STEPS)                       // prefetch before spin
                xn = xg[(size_t)(t + 1) * G4 + grow];
            const uint32_t fw = (uint32_t)(t + 1);
            for (;;) {
                uint32_t f = (l < NW)
                    ? __hip_atomic_load(&pflag[p][l], __ATOMIC_ACQUIRE,
                                        __HIP_MEMORY_SCOPE_WORKGROUP)
                    : fw;
                if (__all(f == fw)) break;
            }
            float s0 = 0.f, s1 = 0.f, s2 = 0.f, s3 = 0.f;
#pragma unroll
            for (int ww = 0; ww < NW; ww += 4) {
                s0 += part[p][ww + 0][l];
                s1 += part[p][ww + 1][l];
                s2 += part[p][ww + 2][l];
                s3 += part[p][ww + 3][l];
            }
            float pre = ((s0 + s1) + (s2 + s3)) + xv;
            // quad exchange: every lane of a quad gets all 4 gate pre-acts
            float pi = quad_bcast<0x00>(pre);
            float pf = quad_bcast<0x55>(pre);
            float pg = quad_bcast<0xAA>(pre);
            float po = quad_bcast<0xFF>(pre);
            float ig = sigm_f(pi), fg = sigm_f(pf);
            float gv = tanh_f(pg), og = sigm_f(po);
            c = fg * c + ig * gv;                      // identical across quad
            float h = og * tanh_f(c);
            if (gate == 0) {                           // 16 lanes, one line
                u64 pub = ((u64)fw << 32) | (u64)__float_as_uint(h);
                __hip_atomic_store(&hdata[((size_t)p << 10) + b * NW + h16], pub,
                                   __ATOMIC_RELAXED, __HIP_MEMORY_SCOPE_AGENT);
                hs[(size_t)(t + 1) * HID + b * NW + h16] = h;  // epilogue copy
            }
            xv = xn;
        }
    }
}

// ---------------------------------------------------------------------------
// Kernel 3: logits = hs @ W_lin^T + b_lin ; softmax over O=2. (unchanged)
// ---------------------------------------------------------------------------
__global__ __launch_bounds__(256) void proj_softmax(
    const float* __restrict__ hs,    // [(T+1)][1024], rows 1..T are h_t
    const float* __restrict__ Wl,    // [2][1024]
    const float* __restrict__ bl,    // [2]
    float* __restrict__ out)         // [T][2]
{
    const int tid = threadIdx.x;
    const int w = tid >> 6, l = tid & 63;
    const int row = blockIdx.x * 4 + w;            // 0..8191
    const float* h = &hs[(size_t)(row + 1) * HID];

    float a0 = 0.f, a1 = 0.f;
#pragma unroll
    for (int i = 0; i < 4; ++i) {
        float4 hv = *(const float4*)&h[256 * i + 4 * l];
        float4 w0 = *(const float4*)&Wl[256 * i + 4 * l];
        float4 w1 = *(const float4*)&Wl[HID + 256 * i + 4 * l];
        a0 = fmaf(hv.x, w0.x, a0); a0 = fmaf(hv.y, w0.y, a0);
        a0 = fmaf(hv.z, w0.z, a0); a0 = fmaf(hv.w, w0.w, a0);
        a1 = fmaf(hv.x, w1.x, a1); a1 = fmaf(hv.y, w1.y, a1);
        a1 = fmaf(hv.z, w1.z, a1); a1 = fmaf(hv.w, w1.w, a1);
    }
#pragma unroll
    for (int off = 1; off < 64; off <<= 1) {
        a0 += __shfl_xor(a0, off, 64);
        a1 += __shfl_xor(a1, off, 64);
    }
    if (l == 0) {
        float l0 = a0 + bl[0];
        float l1 = a1 + bl[1];
        float m  = fmaxf(l0, l1);
        float e0 = __expf(l0 - m), e1 = __expf(l1 - m);
        float inv = 1.f / (e0 + e1);
        float2 o = make_float2(e0 * inv, e1 * inv);
        *(float2*)&out[(size_t)row * 2] = o;
    }
}

// ---------------------------------------------------------------------------
extern "C" void kernel_launch(void* const* d_in, const int* in_sizes, int n_in,
                              void* d_out, int out_size, void* d_ws, size_t ws_size,
                              hipStream_t stream)
{
    const float* input = (const float*)d_in[0];   // [8192][512]
    const float* W_ih  = (const float*)d_in[1];   // [4096][512]
    const float* W_hh  = (const float*)d_in[2];   // [4096][1024]
    const float* b_ih  = (const float*)d_in[3];   // [4096]
    const float* b_hh  = (const float*)d_in[4];   // [4096]
    const float* W_lin = (const float*)d_in[5];   // [2][1024]
    const float* b_lin = (const float*)d_in[6];   // [2]
    float* out = (float*)d_out;                   // [8192][2]

    char* ws = (char*)d_ws;
    float* hs     = (float*)ws;                          // (T+1)*1024 f32
    size_t hs_b   = (size_t)(T_STEPS + 1) * HID * sizeof(float);
    u64*   hdata  = (u64*)(ws + hs_b);                   // 2*1024 u64
    size_t hd_b   = 2 * 1024 * sizeof(u64);
    float* xg     = (float*)(ws + hs_b + hd_b);          // T*4096 f32

    // No memsets needed: 0xAA poison (0xAAAAAAAA) never equals a valid tag
    // (1..8192), hs row 0 is never read, and t=0 uses in-register zeros.

    dim3 g1(G4 / 128, T_STEPS / 128);
    gemm_xgates<<<g1, 256, 0, stream>>>(input, W_ih, b_ih, b_hh, xg);

    lstm_rec<<<NBLK, NW * 64, 0, stream>>>(W_hh, xg, hs, hdata);

    proj_softmax<<<T_STEPS / 4, 256, 0, stream>>>(hs, W_lin, b_lin, out);
}